// Round 9
// baseline (163.625 us; speedup 1.0000x reference)
//
#include <hip/hip_runtime.h>
#include <hip/hip_bf16.h>
#include <math.h>

#define NTOT 16384
#define NP   8192
#define NQ   8192
#define DIM  128
#define TLO   -6.5f            // table low edge  (g flat = 18.4207 below)
#define CELL  0.16875f         // (4.3 - (-6.5)) / 64
#define INV_CELL 5.925925926f  // 1/CELL
#define INV_SQRT2 0.70710678118654752f

typedef float f32x4 __attribute__((ext_vector_type(4)));
typedef __bf16 bf16x8 __attribute__((ext_vector_type(8)));

__device__ __forceinline__ float wave_reduce_sum(float v) {
#pragma unroll
    for (int off = 32; off > 0; off >>= 1)
        v += __shfl_xor(v, off, 64);
    return v;
}

__device__ __forceinline__ unsigned f32_to_bf16_rne(float f) {
    unsigned u = __float_as_uint(f);
    u += 0x7FFFu + ((u >> 16) & 1u);
    return u >> 16;
}

// ---------------------------------------------------------------------------
// Kernel A: per-row separable sums + bf16 packing of the GEMM operands.
//   positives (rows 0..NP-1): rowPack[i] = (1 - sP[i], 2*t1[i]), pv[i][d]=bf16(mu*varA)
//   negatives (rows NP..N-1): colPack[j] = (sN[j],    2*t2[j]), nb[j][d]=bf16(mu)
// Block 0 thread 0 zeroes the output accumulator.
// ---------------------------------------------------------------------------
__global__ __launch_bounds__(256)
void ptl_prep(const float* __restrict__ means,
              const float* __restrict__ vars,
              __hip_bfloat16* __restrict__ pv,
              __hip_bfloat16* __restrict__ nb,
              float2* __restrict__ rowPack,
              float2* __restrict__ colPack,
              float* __restrict__ out)
{
    const int wid  = threadIdx.x >> 6;
    const int lane = threadIdx.x & 63;
    const int r    = (blockIdx.x << 2) + wid;
    const int d    = lane << 1;

    if (blockIdx.x == 0 && threadIdx.x == 0) out[0] = 0.f;

    const float2 mu   = *reinterpret_cast<const float2*>(means + (size_t)r * DIM + d);
    const float2 var  = *reinterpret_cast<const float2*>(vars  + (size_t)r * DIM + d);
    const float2 muA  = *reinterpret_cast<const float2*>(means + d);
    const float2 varA = *reinterpret_cast<const float2*>(vars  + d);

    float s = 0.f, t = 0.f;
    {
        const float m = mu.x, v = var.x, ma = muA.x, va = varA.x;
        const float m2 = m * m, ma2 = ma * ma;
        s += m2 + v - 2.f * ma * m;
        t += v * v + 2.f * m2 * v + 2.f * (va + ma2) * (v + m2)
           - 2.f * ma2 * m2 - 4.f * ma * m * v;
    }
    {
        const float m = mu.y, v = var.y, ma = muA.y, va = varA.y;
        const float m2 = m * m, ma2 = ma * ma;
        s += m2 + v - 2.f * ma * m;
        t += v * v + 2.f * m2 * v + 2.f * (va + ma2) * (v + m2)
           - 2.f * ma2 * m2 - 4.f * ma * m * v;
    }
    s = wave_reduce_sum(s);
    t = wave_reduce_sum(t);

    if (r < NP) {
        __hip_bfloat162 pb;
        pb.x = __float2bfloat16(mu.x * varA.x);
        pb.y = __float2bfloat16(mu.y * varA.y);
        *reinterpret_cast<__hip_bfloat162*>(pv + (size_t)r * DIM + d) = pb;
        if (lane == 0) rowPack[r] = make_float2(1.f - s, 2.f * t);
    } else {
        const int q = r - NP;
        __hip_bfloat162 qb;
        qb.x = __float2bfloat16(mu.x);
        qb.y = __float2bfloat16(mu.y);
        *reinterpret_cast<__hip_bfloat162*>(nb + (size_t)q * DIM + d) = qb;
        if (lane == 0) colPack[q] = make_float2(s, 2.f * t);
    }
}

// ---------------------------------------------------------------------------
// Kernel B: cross-GEMM (bf16 MFMA, K=128) + register-table epilogue.
// NO LDS for data: the 64-cell lerp table of g(x) = -ln(Phi(x)+1e-8) lives in
// one packed u32 per lane (bf16 g | bf16 dg), gathered via ds_bpermute
// (conflict-free, no staging, no barrier). rowPack/colPack are loaded ONCE
// per wave (lane-parallel) and redistributed via ds_bpermute — zero global
// loads inside the epilogue loop. Attacks round-5's latency floor
// (VALUBusy 29%, MfmaUtil 8%, nothing saturated).
// ---------------------------------------------------------------------------
__global__ __launch_bounds__(256, 4)
void ptl_main(const __hip_bfloat16* __restrict__ pv,
              const __hip_bfloat16* __restrict__ nb,
              const float2* __restrict__ rowPack,
              const float2* __restrict__ colPack,
              const float* __restrict__ nmul,
              float* __restrict__ out)
{
    const int wid  = threadIdx.x >> 6;
    const int lane = threadIdx.x & 63;
    const int bi   = blockIdx.x >> 6;
    const int bj   = blockIdx.x & 63;
    const int wr   = wid >> 1, wc = wid & 1;
    const int i0   = bi * 128 + wr * 64;
    const int j0   = bj * 128 + wc * 64;
    const int l16  = lane & 15;
    const int l4   = lane >> 4;

    // --- per-lane table cell: [xlo, xlo+CELL), packed (bf16 dg | bf16 g) ---
    const float xlo = TLO + (float)lane * CELL;
    const float ga  = -logf(0.5f * erfcf(-xlo * INV_SQRT2) + 1e-8f);
    const float gb  = -logf(0.5f * erfcf(-(xlo + CELL) * INV_SQRT2) + 1e-8f);
    const int tblpk = (int)((f32_to_bf16_rne(gb - ga) << 16) | f32_to_bf16_rne(ga));

    // --- wave-resident row/col packs (one coalesced load each) ---
    const float2 rpl = rowPack[i0 + lane];
    const float2 cpl = colPack[j0 + lane];
    const int rpx = __float_as_int(rpl.x), rpy = __float_as_int(rpl.y);
    const int cpx = __float_as_int(cpl.x), cpy = __float_as_int(cpl.y);

    f32x4 acc[4][4];
#pragma unroll
    for (int m = 0; m < 4; ++m)
#pragma unroll
        for (int n = 0; n < 4; ++n)
            acc[m][n] = (f32x4){0.f, 0.f, 0.f, 0.f};

    const __hip_bfloat16* Ab = pv + (size_t)(i0 + l16) * DIM + l4 * 8;
    const __hip_bfloat16* Bb = nb + (size_t)(j0 + l16) * DIM + l4 * 8;

#pragma unroll
    for (int kq = 0; kq < 4; ++kq) {
        bf16x8 a[4], b[4];
#pragma unroll
        for (int m = 0; m < 4; ++m)
            a[m] = *reinterpret_cast<const bf16x8*>(Ab + m * 16 * DIM + kq * 32);
#pragma unroll
        for (int n = 0; n < 4; ++n)
            b[n] = *reinterpret_cast<const bf16x8*>(Bb + n * 16 * DIM + kq * 32);
#pragma unroll
        for (int m = 0; m < 4; ++m)
#pragma unroll
            for (int n = 0; n < 4; ++n)
                acc[m][n] = __builtin_amdgcn_mfma_f32_16x16x32_bf16(a[m], b[n], acc[m][n], 0, 0, 0);
    }

    // cp values for this wave's 4 column groups (bpermute, no memory)
    float cpx_[4], cpy_[4];
#pragma unroll
    for (int n = 0; n < 4; ++n) {
        const int idx = (n * 16 + l16) << 2;
        cpx_[n] = __int_as_float(__builtin_amdgcn_ds_bpermute(idx, cpx));
        cpy_[n] = __int_as_float(__builtin_amdgcn_ds_bpermute(idx, cpy));
    }

    float lacc0 = 0.f, lacc1 = 0.f, lacc2 = 0.f, lacc3 = 0.f;
#pragma unroll
    for (int m = 0; m < 4; ++m) {
        float rpx_[4], rpy_[4];
#pragma unroll
        for (int rr = 0; rr < 4; ++rr) {
            const int idx = (m * 16 + l4 * 4 + rr) << 2;
            rpx_[rr] = __int_as_float(__builtin_amdgcn_ds_bpermute(idx, rpx));
            rpy_[rr] = __int_as_float(__builtin_amdgcn_ds_bpermute(idx, rpy));
        }

        // Phase A: 16 clamped cell coordinates
        float us[16];
#pragma unroll
        for (int n = 0; n < 4; ++n) {
#pragma unroll
            for (int rr = 0; rr < 4; ++rr) {
                const float c   = acc[m][n][rr];
                const float t12 = rpy_[rr] + cpy_[n];        // 2t1 + 2t2
                const float omm = rpx_[rr] + cpx_[n];        // 1 - mu
                float s2 = fmaf(-8.f, c, t12);               // sigma^2
                s2 = fmaxf(s2, 1e-20f);
                const float x = omm * __builtin_amdgcn_rsqf(s2);
                float u = fmaf(x, INV_CELL, 38.5185185f);    // (x - TLO)/CELL
                us[n * 4 + rr] = __builtin_amdgcn_fmed3f(u, 0.0f, 63.99f);
            }
        }

        // Phase B: 16 independent bpermute gathers (DS pipe, conflict-free)
        int pk[16];
#pragma unroll
        for (int e = 0; e < 16; ++e)
            pk[e] = __builtin_amdgcn_ds_bpermute(((int)us[e]) << 2, tblpk);

        // Phase C: lerp + accumulate (4 chains)
#pragma unroll
        for (int e = 0; e < 16; ++e) {
            const float fr = us[e] - (float)((int)us[e]);
            const float g  = __int_as_float(pk[e] << 16);
            const float dg = __int_as_float(pk[e] & 0xFFFF0000);
            const float val = fmaf(fr, dg, g);
            if ((e & 3) == 0) lacc0 += val;
            else if ((e & 3) == 1) lacc1 += val;
            else if ((e & 3) == 2) lacc2 += val;
            else lacc3 += val;
        }
    }

    float lsum = (lacc0 + lacc1) + (lacc2 + lacc3);
    lsum = wave_reduce_sum(lsum);

    __shared__ float wsum[4];
    if (lane == 0) wsum[wid] = lsum;
    __syncthreads();
    if (threadIdx.x == 0) {
        const float bsum = (wsum[0] + wsum[1]) + (wsum[2] + wsum[3]);
        const float cst = nmul[0] / (0.5f * (float)NP * (float)NQ);
        atomicAdd(out, cst * bsum);    // g already = -log(probs+eps)
    }
}

extern "C" void kernel_launch(void* const* d_in, const int* in_sizes, int n_in,
                              void* d_out, int out_size, void* d_ws, size_t ws_size,
                              hipStream_t stream)
{
    const float* means = (const float*)d_in[1];   // est_means [N, D] f32
    const float* vars  = (const float*)d_in[2];   // est_vars  [N, D] f32
    const float* nmul  = (const float*)d_in[3];   // NmulPnN scalar f32
    float* out = (float*)d_out;

    __hip_bfloat16* pv = (__hip_bfloat16*)d_ws;                 // [NP,128] bf16 (2 MB)
    __hip_bfloat16* nb = pv + (size_t)NP * DIM;                 // [NQ,128] bf16 (2 MB)
    float2* rowPack = (float2*)((char*)d_ws + (size_t)(NP + NQ) * DIM * sizeof(__hip_bfloat16));
    float2* colPack = rowPack + NP;

    ptl_prep<<<NTOT / 4, 256, 0, stream>>>(means, vars, pv, nb, rowPack, colPack, out);
    ptl_main<<<(NP / 128) * (NQ / 128), 256, 0, stream>>>(pv, nb, rowPack, colPack, nmul, out);
}